// Round 8
// baseline (303.538 us; speedup 1.0000x reference)
//
#include <hip/hip_runtime.h>
#include <stdint.h>

typedef short bf16x8 __attribute__((ext_vector_type(8)));
typedef float f32x4  __attribute__((ext_vector_type(4)));

__device__ __forceinline__ uint32_t bfbits(float f) {
    uint32_t u = __builtin_bit_cast(uint32_t, f);
    u += 0x7FFFu + ((u >> 16) & 1u);   // round-to-nearest-even
    return u >> 16;
}
__device__ __forceinline__ uint32_t pk2(float a, float b) {
    return bfbits(a) | (bfbits(b) << 16);
}

// x (f32) -> xb (bf16), 8 elems/thread/iter, grid-stride
__global__ void xcvt_kernel(const float* __restrict__ x, short* __restrict__ xb, int n8) {
    int i = blockIdx.x * 256 + threadIdx.x;
    const int stride = gridDim.x * 256;
    for (; i < n8; i += stride) {
        f32x4 a = *(const f32x4*)(x + (size_t)i * 8);
        f32x4 b = *(const f32x4*)(x + (size_t)i * 8 + 4);
        uint4 r;
        r.x = pk2(a[0], a[1]); r.y = pk2(a[2], a[3]);
        r.z = pk2(b[0], b[1]); r.w = pk2(b[2], b[3]);
        *(uint4*)(xb + (size_t)i * 8) = r;
    }
}

// Wt[t][c][j][ic] = bf16(W[dy][dx][ic][j*4+c]); quadrant c owns oc = j*4+c.
__global__ void wt_kernel(const float* __restrict__ W, short* __restrict__ Wt) {
    int idx = blockIdx.x * 256 + threadIdx.x;      // 9*4*64*64 = 147456
    if (idx >= 147456) return;
    int t  = idx >> 14;
    int r  = idx & 16383;
    int c  = r >> 12;
    int j  = (r >> 6) & 63;
    int ic = r & 63;
    Wt[idx] = (short)bfbits(W[(t * 64 + ic) * 256 + j * 4 + c]);
}

#define NT 6
#define A_SLOT 4224              // shorts per h-row slot: 66 wpos * 64 ic
#define A_SH   (10 * A_SLOT)     // 84,480 B (10-row ring)
#define B_SH   (9 * 64 * 64)     // 73,728 B (9 taps x 64 j x 64 ic)
// total 158,208 B -> 1 block/CU (8 waves, 2/SIMD)

// Implicit-GEMM conv3x3 + bias + pixel_shuffle quadrant, bf16 MFMA.
// Block: 8 waves, wave = 1 h-row x 64 w x 64 j -> 0.5 ds_read per MFMA
// (LDS-pipe floor ~104us). B resident, A ring + bf16 register prefetch.
// acc ping-pong + lgkm-only barriers: store drain overlaps next tile.
template <int XBF>
__global__ __launch_bounds__(512, 1) void conv_ps_kernel(
    const float* __restrict__ x, const short* __restrict__ xb,
    const short* __restrict__ Wt, const float* __restrict__ bias,
    float* __restrict__ out)
{
    __shared__ short smem[A_SH + B_SH];   // 158,208 B
    short* As = smem;
    short* Bs = smem + A_SH;

    const int tid   = threadIdx.x;
    const int lane  = tid & 63;
    const int wv    = tid >> 6;       // which of 8 h-rows in the tile
    const int row_l = lane & 15;
    const int grp   = lane >> 4;
    const int b7    = row_l & 7;

    // XCD-aware bijective swizzle (nwg = 768 % 8 == 0); c innermost so the 4
    // quadrant-siblings sharing an x-region land on the same XCD's L2.
    const int raw = blockIdx.x;
    const int lb  = (raw & 7) * 96 + (raw >> 3);
    const int c   = lb & 3;
    const int wt  = (lb >> 2) % 3;
    const int hg  = (lb / 12) & 3;
    const int n   = lb / 48;
    const int w0  = wt * 64;
    const int hbase = hg * 48;
    const int q = c & 1, p = (c >> 1) & 1;

    // ---- prologue: B once (write-side XOR swizzle on 16B slots) ----
    {
        const short* wsrc = Wt + c * 4096;         // [t][c][j][ic], t-stride 16384
        #pragma unroll
        for (int k = 0; k < 9; ++k) {
            int cid = tid + k * 512;               // 0..4607
            int t = cid >> 9, j = (cid >> 3) & 63, s = cid & 7;
            bf16x8 v = *(const bf16x8*)(wsrc + t * 16384 + j * 64 + s * 8);
            *(bf16x8*)&Bs[t * 4096 + j * 64 + ((s ^ (j & 7)) << 3)] = v;
        }
    }
    // ---- prologue: A ring, rows hbase-1 .. hbase+8 (10 rows) ----
    if (XBF) {
        #pragma unroll
        for (int k = 0; k < 11; ++k) {
            int cid = tid + k * 512;               // 0..5279 valid (10*66*8)
            if (cid < 5280) {
                int rl   = cid / 528;
                int rem  = cid - rl * 528;
                int wpos = rem >> 3;
                int g    = rem & 7;
                int r_abs = hbase - 1 + rl;
                int wg    = w0 - 1 + wpos;
                bf16x8 v = {};
                if ((unsigned)r_abs < 192u && (unsigned)wg < 192u)
                    v = *(const bf16x8*)(xb + (((size_t)n * 192 + r_abs) * 192 + wg) * 64 + g * 8);
                int slot = (hbase + rl) % 10;
                *(bf16x8*)&As[slot * A_SLOT + wpos * 64 + ((g ^ (wpos & 7)) << 3)] = v;
            }
        }
    } else {
        #pragma unroll
        for (int k = 0; k < 21; ++k) {
            int cid = tid + k * 512;               // 0..10559 valid
            if (cid < 10560) {
                int rl   = cid / 1056;
                int rem  = cid - rl * 1056;
                int wpos = rem >> 4;
                int c4   = rem & 15;
                int r_abs = hbase - 1 + rl;
                int wg    = w0 - 1 + wpos;
                f32x4 v = {0.f, 0.f, 0.f, 0.f};
                if ((unsigned)r_abs < 192u && (unsigned)wg < 192u)
                    v = *(const f32x4*)(x + (((size_t)n * 192 + r_abs) * 192 + wg) * 64 + c4 * 4);
                int slot = (hbase + rl) % 10;
                uint2 pr; pr.x = pk2(v[0], v[1]); pr.y = pk2(v[2], v[3]);
                *(uint2*)&As[slot * A_SLOT + wpos * 64 +
                             (((c4 >> 1) ^ (wpos & 7)) << 3) + (c4 & 1) * 4] = pr;
            }
        }
    }
    __syncthreads();

    float bv[4];
    #pragma unroll
    for (int nt = 0; nt < 4; ++nt)
        bv[nt] = bias[(nt * 16 + row_l) * 4 + c];

    f32x4 accA[4][4], accB[4][4];

    auto do_tile = [&](f32x4 (&acc)[4][4], int it) {
        const int h0 = hbase + it * 8;
        const bool pf = (it < NT - 1);

        // 1. issue next tile's 8 fresh rows (h0+9 .. h0+16) into registers
        bf16x8 stgb[9];
        f32x4  stgf[17];
        if (pf) {
            if (XBF) {
                #pragma unroll
                for (int k = 0; k < 9; ++k) {
                    int cid = tid + k * 512;       // 0..4223 valid (8*66*8)
                    bf16x8 v = {};
                    if (cid < 4224) {
                        int rl   = cid / 528;
                        int rem  = cid - rl * 528;
                        int wpos = rem >> 3;
                        int g    = rem & 7;
                        int r_abs = h0 + 9 + rl;
                        int wg    = w0 - 1 + wpos;
                        if (r_abs < 192 && (unsigned)wg < 192u)
                            v = *(const bf16x8*)(xb + (((size_t)n * 192 + r_abs) * 192 + wg) * 64 + g * 8);
                    }
                    stgb[k] = v;
                }
            } else {
                #pragma unroll
                for (int k = 0; k < 17; ++k) {
                    int cid = tid + k * 512;       // 0..8447 valid
                    f32x4 v = {0.f, 0.f, 0.f, 0.f};
                    if (cid < 8448) {
                        int rl   = cid / 1056;
                        int rem  = cid - rl * 1056;
                        int wpos = rem >> 4;
                        int c4   = rem & 15;
                        int r_abs = h0 + 9 + rl;
                        int wg    = w0 - 1 + wpos;
                        if (r_abs < 192 && (unsigned)wg < 192u)
                            v = *(const f32x4*)(x + (((size_t)n * 192 + r_abs) * 192 + wg) * 64 + c4 * 4);
                    }
                    stgf[k] = v;
                }
            }
        }

        // 2. acc starts at bias (fused bias add)
        #pragma unroll
        for (int i = 0; i < 4; ++i)
            #pragma unroll
            for (int j = 0; j < 4; ++j)
                acc[i][j] = (f32x4){bv[j], bv[j], bv[j], bv[j]};

        // 3. compute: full K=576 for this wave's 64x64 tile, barrier-free
        int sl[3];
        #pragma unroll
        for (int dy = 0; dy < 3; ++dy) sl[dy] = (h0 + wv + dy) % 10;

        #pragma unroll
        for (int dy = 0; dy < 3; ++dy) {
            #pragma unroll
            for (int dx = 0; dx < 3; ++dx) {
                const int t  = dy * 3 + dx;
                const int rd = row_l + dx;
                const int a7 = rd & 7;
                const int aB = sl[dy] * A_SLOT + rd * 64;
                const int bB = t * 4096 + row_l * 64;
                #pragma unroll
                for (int ks = 0; ks < 2; ++ks) {
                    const int kg = ks * 4 + grp;
                    const short* ap = &As[aB + ((kg ^ a7) << 3)];
                    const short* bp = &Bs[bB + ((kg ^ b7) << 3)];
                    bf16x8 af[4], bfr[4];
                    #pragma unroll
                    for (int mt = 0; mt < 4; ++mt) af[mt]  = *(const bf16x8*)(ap + mt * 1024);
                    #pragma unroll
                    for (int nt = 0; nt < 4; ++nt) bfr[nt] = *(const bf16x8*)(bp + nt * 1024);
                    #pragma unroll
                    for (int mt = 0; mt < 4; ++mt)
                        #pragma unroll
                        for (int nt = 0; nt < 4; ++nt)
                            acc[mt][nt] = __builtin_amdgcn_mfma_f32_16x16x32_bf16(
                                af[mt], bfr[nt], acc[mt][nt], 0, 0, 0);
                }
            }
        }

        // 4. stores: issue and DO NOT wait — they drain under the next tile.
        {
            const int h = h0 + wv;
            const long rowb = ((long)(n * 384 + 2 * h + q)) * 384;
            #pragma unroll
            for (int mt = 0; mt < 4; ++mt) {
                float* po = out + ((rowb + 2 * (w0 + mt * 16 + grp * 4) + p) * 64 + row_l);
                #pragma unroll
                for (int nt = 0; nt < 4; ++nt)
                    #pragma unroll
                    for (int jv = 0; jv < 4; ++jv)
                        po[jv * 128 + nt * 16] = acc[mt][nt][jv];
            }
        }

        // 5. ring rotate: lgkm-only barriers (no vmcnt drain of the stores)
        if (pf) {
            asm volatile("s_waitcnt lgkmcnt(0)" ::: "memory");
            __builtin_amdgcn_sched_barrier(0);
            __builtin_amdgcn_s_barrier();          // all waves done reading ring
            asm volatile("" ::: "memory");
            __builtin_amdgcn_sched_barrier(0);

            if (XBF) {
                #pragma unroll
                for (int k = 0; k < 9; ++k) {
                    int cid = tid + k * 512;
                    if (cid < 4224) {
                        int rl   = cid / 528;
                        int rem  = cid - rl * 528;
                        int wpos = rem >> 3;
                        int g    = rem & 7;
                        int slot = (h0 + 10 + rl) % 10;
                        *(bf16x8*)&As[slot * A_SLOT + wpos * 64 + ((g ^ (wpos & 7)) << 3)] = stgb[k];
                    }
                }
            } else {
                #pragma unroll
                for (int k = 0; k < 17; ++k) {
                    int cid = tid + k * 512;
                    if (cid < 8448) {
                        int rl   = cid / 1056;
                        int rem  = cid - rl * 1056;
                        int wpos = rem >> 4;
                        int c4   = rem & 15;
                        int slot = (h0 + 10 + rl) % 10;
                        uint2 pr; pr.x = pk2(stgf[k][0], stgf[k][1]);
                        pr.y = pk2(stgf[k][2], stgf[k][3]);
                        *(uint2*)&As[slot * A_SLOT + wpos * 64 +
                                     (((c4 >> 1) ^ (wpos & 7)) << 3) + (c4 & 1) * 4] = pr;
                    }
                }
            }
            asm volatile("s_waitcnt lgkmcnt(0)" ::: "memory");
            __builtin_amdgcn_sched_barrier(0);
            __builtin_amdgcn_s_barrier();          // new rows visible
            asm volatile("" ::: "memory");
            __builtin_amdgcn_sched_barrier(0);
        }
    };

    #pragma unroll 1
    for (int itp = 0; itp < NT; itp += 2) {
        do_tile(accA, itp);
        do_tile(accB, itp + 1);
    }
}

extern "C" void kernel_launch(void* const* d_in, const int* in_sizes, int n_in,
                              void* d_out, int out_size, void* d_ws, size_t ws_size,
                              hipStream_t stream) {
    const float* x = (const float*)d_in[0];
    const float* W = (const float*)d_in[1];
    const float* b = (const float*)d_in[2];
    float* out = (float*)d_out;

    const size_t xb_bytes = (size_t)16 * 192 * 192 * 64 * 2;   // 75,497,472
    const size_t wt_bytes = 294912;

    if (ws_size >= xb_bytes + wt_bytes) {
        short* xb = (short*)d_ws;
        short* Wt = (short*)((char*)d_ws + xb_bytes);
        hipLaunchKernelGGL(xcvt_kernel, dim3(2048), dim3(256), 0, stream, x, xb, 4718592);
        hipLaunchKernelGGL(wt_kernel, dim3(576), dim3(256), 0, stream, W, Wt);
        hipLaunchKernelGGL((conv_ps_kernel<1>), dim3(768), dim3(512), 0, stream,
                           x, xb, Wt, b, out);
    } else {
        short* Wt = (short*)d_ws;
        hipLaunchKernelGGL(wt_kernel, dim3(576), dim3(256), 0, stream, W, Wt);
        hipLaunchKernelGGL((conv_ps_kernel<0>), dim3(768), dim3(512), 0, stream,
                           x, (const short*)nullptr, Wt, b, out);
    }
}

// Round 9
// 277.849 us; speedup vs baseline: 1.0925x; 1.0925x over previous
//
#include <hip/hip_runtime.h>
#include <stdint.h>

typedef short bf16x8 __attribute__((ext_vector_type(8)));
typedef float f32x4  __attribute__((ext_vector_type(4)));

#define GLOAD_LDS16(gp, lp) \
    __builtin_amdgcn_global_load_lds((const __attribute__((address_space(1))) void*)(gp), \
                                     (__attribute__((address_space(3))) void*)(lp), 16, 0, 0)

__device__ __forceinline__ uint32_t bfbits(float f) {
    uint32_t u = __builtin_bit_cast(uint32_t, f);
    u += 0x7FFFu + ((u >> 16) & 1u);   // round-to-nearest-even
    return u >> 16;
}
__device__ __forceinline__ uint32_t pk2(float a, float b) {
    return bfbits(a) | (bfbits(b) << 16);
}

// x (f32, [16][192][192][64]) -> xb (bf16, PADDED [16][194][194][64], zero halo)
__global__ void xcvt_kernel(const float* __restrict__ x, short* __restrict__ xb) {
    const int total = 16 * 194 * 194 * 8;          // 16B chunks
    for (int i = blockIdx.x * 256 + threadIdx.x; i < total; i += gridDim.x * 256) {
        int g  = i & 7;
        int t  = i >> 3;
        int wp = t % 194; t /= 194;
        int hp = t % 194;
        int nn = t / 194;
        uint4 r = {0u, 0u, 0u, 0u};
        if (hp >= 1 && hp <= 192 && wp >= 1 && wp <= 192) {
            const float* s = x + (((size_t)nn * 192 + (hp - 1)) * 192 + (wp - 1)) * 64 + g * 8;
            f32x4 a = *(const f32x4*)s;
            f32x4 b = *(const f32x4*)(s + 4);
            r.x = pk2(a[0], a[1]); r.y = pk2(a[2], a[3]);
            r.z = pk2(b[0], b[1]); r.w = pk2(b[2], b[3]);
        }
        *(uint4*)(xb + (size_t)i * 8) = r;
    }
}

// Wt[t][c][j][ic] = bf16(W[dy][dx][ic][j*4+c]); quadrant c owns oc = j*4+c.
__global__ void wt_kernel(const float* __restrict__ W, short* __restrict__ Wt) {
    int idx = blockIdx.x * 256 + threadIdx.x;      // 9*4*64*64 = 147456
    if (idx >= 147456) return;
    int t  = idx >> 14;
    int r  = idx & 16383;
    int c  = r >> 12;
    int j  = (r >> 6) & 63;
    int ic = r & 63;
    Wt[idx] = (short)bfbits(W[(t * 64 + ic) * 256 + j * 4 + c]);
}

#define NT 6
#define A_SLOT 4224              // shorts per h-row slot: 66 wpos * 64 ic (8448 B = 528 chunks)
#define A_SH   (10 * A_SLOT)     // 84,480 B (10-row ring)
#define B_SH   (9 * 64 * 64)     // 73,728 B (9 taps x 64 j x 64 ic)
// total 158,208 B -> 1 block/CU (8 waves, 2/SIMD)

// Implicit-GEMM conv3x3 + bias + pixel_shuffle quadrant, bf16 MFMA.
// Wave = 1 h-row x 64 w x 64 j -> 0.5 ds_read_b128 per MFMA (LDS floor ~104us).
// A ring refilled by global_load_lds from PADDED bf16 xb (pre-swizzled source,
// linear dest, swizzled read). Single acc; counted-vmcnt tile boundary so
// epilogue stores drain under the next tile's compute.
__global__ __launch_bounds__(512, 2) void conv_ps_kernel(
    const short* __restrict__ xb, const short* __restrict__ Wt,
    const float* __restrict__ bias, float* __restrict__ out)
{
    __shared__ short smem[ (A_SH + B_SH) ];   // 158,208 B
    short* As = smem;
    short* Bs = smem + A_SH;

    const int tid   = threadIdx.x;
    const int lane  = tid & 63;
    const int wv    = tid >> 6;       // which of 8 h-rows in the tile
    const int row_l = lane & 15;
    const int grp   = lane >> 4;
    const int b7    = row_l & 7;

    // XCD-aware bijective swizzle (nwg = 768 % 8 == 0); c innermost.
    const int raw = blockIdx.x;
    const int lb  = (raw & 7) * 96 + (raw >> 3);
    const int c   = lb & 3;
    const int wt  = (lb >> 2) % 3;
    const int hg  = (lb / 12) & 3;
    const int n   = lb / 48;
    const int w0  = wt * 64;
    const int hbase = hg * 48;
    const int q = c & 1, p = (c >> 1) & 1;

    // ---- prologue: B via global_load_lds (9 taps x 512 chunks = 72 instrs) ----
    {
        const short* wsrc = Wt + c * 4096;         // [t][c][j][ic], t-stride 16384
        for (int k = wv; k < 72; k += 8) {
            int t   = k >> 3, j8 = k & 7;
            int cch = j8 * 64 + lane;              // chunk within tap: j*8 + s'
            int j   = cch >> 3, s1 = cch & 7;
            int ss  = s1 ^ (j & 7);                // pre-swizzled source slot
            GLOAD_LDS16(wsrc + t * 16384 + j * 64 + ss * 8,
                        (char*)Bs + t * 8192 + j8 * 1024);
        }
    }
    // ---- prologue: A ring rows hbase-1 .. hbase+8 (10 rows x 9 instrs) ----
    for (int k = wv; k < 90; k += 8) {
        int rl  = k / 9, jj = k % 9;
        int row = hbase - 1 + rl;
        int slot = (row + 1) % 10;
        int cch = jj * 64 + lane;                  // 0..575 (valid < 528)
        int wpos = cch >> 3, g1 = cch & 7;
        int gs   = g1 ^ (wpos & 7);                // pre-swizzled source slot
        const short* src = xb + (((size_t)n * 194 + (row + 1)) * 194 + (w0 + wpos)) * 64 + gs * 8;
        void* dst = (char*)As + slot * 8448 + jj * 1024;
        if (jj < 8)            GLOAD_LDS16(src, dst);
        else if (lane < 16)    GLOAD_LDS16(src, dst);   // partial: 16 chunks
    }
    __syncthreads();   // drains vmcnt -> prologue LDS complete

    float bv[4];
    #pragma unroll
    for (int nt = 0; nt < 4; ++nt)
        bv[nt] = bias[(nt * 16 + row_l) * 4 + c];

    #pragma unroll 1
    for (int it = 0; it < NT; ++it) {
        const int h0 = hbase + it * 8;

        // acc starts at bias (fused bias add)
        f32x4 acc[4][4];
        #pragma unroll
        for (int i = 0; i < 4; ++i)
            #pragma unroll
            for (int j = 0; j < 4; ++j)
                acc[i][j] = (f32x4){bv[j], bv[j], bv[j], bv[j]};

        // compute: full K=576 for this wave's 64x64 tile, barrier-free
        int sl[3];
        #pragma unroll
        for (int dy = 0; dy < 3; ++dy) sl[dy] = (h0 + wv + dy) % 10;

        #pragma unroll
        for (int dy = 0; dy < 3; ++dy) {
            #pragma unroll
            for (int dx = 0; dx < 3; ++dx) {
                const int t  = dy * 3 + dx;
                const int rd = row_l + dx;
                const int a7 = rd & 7;
                const int aB = sl[dy] * A_SLOT + rd * 64;
                const int bB = t * 4096 + row_l * 64;
                #pragma unroll
                for (int ks = 0; ks < 2; ++ks) {
                    const int kg = ks * 4 + grp;
                    const short* ap = &As[aB + ((kg ^ a7) << 3)];
                    const short* bp = &Bs[bB + ((kg ^ b7) << 3)];
                    bf16x8 af[4], bfr[4];
                    #pragma unroll
                    for (int mt = 0; mt < 4; ++mt) af[mt]  = *(const bf16x8*)(ap + mt * 1024);
                    #pragma unroll
                    for (int nt = 0; nt < 4; ++nt) bfr[nt] = *(const bf16x8*)(bp + nt * 1024);
                    #pragma unroll
                    for (int mt = 0; mt < 4; ++mt)
                        #pragma unroll
                        for (int nt = 0; nt < 4; ++nt)
                            acc[mt][nt] = __builtin_amdgcn_mfma_f32_16x16x32_bf16(
                                af[mt], bfr[nt], acc[mt][nt], 0, 0, 0);
                }
            }
        }

        const int h = h0 + wv;
        const long rowb = ((long)(n * 384 + 2 * h + q)) * 384;

        if (it < NT - 1) {
            // 1. all waves done READING the ring (ds_reads tracked by lgkmcnt)
            asm volatile("s_waitcnt lgkmcnt(0)" ::: "memory");
            __builtin_amdgcn_sched_barrier(0);
            __builtin_amdgcn_s_barrier();
            __builtin_amdgcn_sched_barrier(0);

            // 2. issue refill: rows h0+9 .. h0+16 (8 rows x 9 instrs = 72)
            for (int k = wv; k < 72; k += 8) {
                int rl  = k / 9, jj = k % 9;
                int row = h0 + 9 + rl;
                int slot = (row + 1) % 10;
                int cch = jj * 64 + lane;
                int wpos = cch >> 3, g1 = cch & 7;
                int gs   = g1 ^ (wpos & 7);
                const short* src = xb + (((size_t)n * 194 + (row + 1)) * 194 + (w0 + wpos)) * 64 + gs * 8;
                void* dst = (char*)As + slot * 8448 + jj * 1024;
                if (jj < 8)         GLOAD_LDS16(src, dst);
                else if (lane < 16) GLOAD_LDS16(src, dst);
            }
            asm volatile("" ::: "memory");         // pin: refills issued before stores
            __builtin_amdgcn_sched_barrier(0);

            // 3. epilogue stores (issue; they drain under the next tile)
            #pragma unroll
            for (int mt = 0; mt < 4; ++mt) {
                float* po = out + ((rowb + 2 * (w0 + mt * 16 + grp * 4) + p) * 64 + row_l);
                #pragma unroll
                for (int nt = 0; nt < 4; ++nt)
                    #pragma unroll
                    for (int jv = 0; jv < 4; ++jv)
                        po[jv * 128 + nt * 16] = acc[mt][nt][jv];
            }

            // 4. wait refills only: 9 refills are OLDER than the 64 stores;
            //    vmcnt(63) completes everything but the newest 63 stores.
            asm volatile("s_waitcnt vmcnt(63)" ::: "memory");
            __builtin_amdgcn_sched_barrier(0);
            __builtin_amdgcn_s_barrier();          // refilled rows visible to all
            __builtin_amdgcn_sched_barrier(0);
        } else {
            #pragma unroll
            for (int mt = 0; mt < 4; ++mt) {
                float* po = out + ((rowb + 2 * (w0 + mt * 16 + grp * 4) + p) * 64 + row_l);
                #pragma unroll
                for (int nt = 0; nt < 4; ++nt)
                    #pragma unroll
                    for (int jv = 0; jv < 4; ++jv)
                        po[jv * 128 + nt * 16] = acc[mt][nt][jv];
            }
        }
    }
}

extern "C" void kernel_launch(void* const* d_in, const int* in_sizes, int n_in,
                              void* d_out, int out_size, void* d_ws, size_t ws_size,
                              hipStream_t stream) {
    const float* x = (const float*)d_in[0];
    const float* W = (const float*)d_in[1];
    const float* b = (const float*)d_in[2];
    float* out = (float*)d_out;

    const size_t xb_bytes = (size_t)16 * 194 * 194 * 64 * 2;   // 77,070,336 (padded)
    short* xbuf = (short*)d_ws;
    short* Wt   = (short*)((char*)d_ws + xb_bytes);

    hipLaunchKernelGGL(xcvt_kernel, dim3(2048), dim3(256), 0, stream, x, xbuf);
    hipLaunchKernelGGL(wt_kernel, dim3(576), dim3(256), 0, stream, W, Wt);
    hipLaunchKernelGGL(conv_ps_kernel, dim3(768), dim3(512), 0, stream, xbuf, Wt, b, out);
}